// Round 9
// baseline (315.615 us; speedup 1.0000x reference)
//
#include <hip/hip_runtime.h>
#include <stdint.h>

typedef int v4i __attribute__((ext_vector_type(4)));

#define DSR(d, b, O) \
  asm volatile("ds_read_b128 %0, %1 offset:" O : "=v"(d) : "v"(b))
#define DSW(b, O, v) \
  asm volatile("ds_write_b128 %0, %1 offset:" O ::"v"(b), "v"(v) : "memory")
#define LGKM0()                                        \
  do {                                                 \
    asm volatile("s_waitcnt lgkmcnt(0)" ::: "memory"); \
    __builtin_amdgcn_sched_barrier(0);                 \
  } while (0)

// ---------------------------------------------------------------------------
__device__ __forceinline__ void fwht16(float v[16]) {
#pragma unroll
  for (int h = 1; h < 16; h <<= 1) {
#pragma unroll
    for (int i = 0; i < 16; ++i) {
      if (!(i & h)) {
        float a = v[i], b = v[i | h];
        v[i] = a + b;
        v[i | h] = a - b;
      }
    }
  }
}

__device__ __forceinline__ void fwht_row_load(const float* __restrict__ xr, int t,
                                              float v[16]) {
  const float4* p = reinterpret_cast<const float4*>(xr) + t * 4;
  float4 a = p[0], b = p[1], c = p[2], d = p[3];
  v[0] = a.x; v[1] = a.y; v[2] = a.z; v[3] = a.w;
  v[4] = b.x; v[5] = b.y; v[6] = b.z; v[7] = b.w;
  v[8] = c.x; v[9] = c.y; v[10] = c.z; v[11] = c.w;
  v[12] = d.x; v[13] = d.y; v[14] = d.z; v[15] = d.w;
}

__device__ __forceinline__ void fwht4096(float v[16], float* lds, int t) {
  fwht16(v);
#pragma unroll
  for (int e = 0; e < 16; ++e) {
    int idx = t * 16 + e;
    lds[idx + (idx >> 5)] = v[e];
  }
  __syncthreads();
#pragma unroll
  for (int e = 0; e < 16; ++e) {
    int idx = ((t >> 4) << 8) + (e << 4) + (t & 15);
    v[e] = lds[idx + (idx >> 5)];
  }
  fwht16(v);
#pragma unroll
  for (int e = 0; e < 16; ++e) {
    int idx = ((t >> 4) << 8) + (e << 4) + (t & 15);
    lds[idx + (idx >> 5)] = v[e];
  }
  __syncthreads();
#pragma unroll
  for (int e = 0; e < 16; ++e) {
    int idx = (e << 8) + t;
    v[e] = lds[idx + (idx >> 5)];
  }
  fwht16(v);
#pragma unroll
  for (int e = 0; e < 16; ++e) v[e] *= 0.015625f;  // 1/sqrt(4096)
}

__global__ __launch_bounds__(256) void fwht_quant_kernel(const float* __restrict__ X,
                                                         int8_t* __restrict__ Q,
                                                         float* __restrict__ S) {
  const int row = blockIdx.x;
  const int t = threadIdx.x;
  __shared__ __align__(16) float lds[4224];
  __shared__ float wred[4];

  float v[16];
  fwht_row_load(X + (size_t)row * 4096, t, v);
  fwht4096(v, lds, t);

  float m = 0.f;
#pragma unroll
  for (int e = 0; e < 16; ++e) m = fmaxf(m, fabsf(v[e]));
#pragma unroll
  for (int off = 32; off > 0; off >>= 1) m = fmaxf(m, __shfl_xor(m, off));
  if ((t & 63) == 0) wred[t >> 6] = m;
  __syncthreads();
  m = fmaxf(fmaxf(wred[0], wred[1]), fmaxf(wred[2], wred[3]));
  const float s = fmaxf(m * (1.0f / 127.0f), 1e-8f);
  if (t == 0) S[row] = s;

  // quantize in regs, byte-transpose via padded LDS, one int4 store/thread.
  __syncthreads();
  char* b8 = (char*)lds;
#pragma unroll
  for (int e = 0; e < 16; ++e) {
    float q = rintf(v[e] / s);
    q = fminf(fmaxf(q, -127.f), 127.f);
    int idx = (e << 8) + t;
    b8[idx + ((idx >> 8) << 4)] = (char)(int)q;
  }
  __syncthreads();
  int4 pack = *reinterpret_cast<const int4*>(b8 + t * 16 + ((t >> 4) << 4));
  reinterpret_cast<int4*>(Q + (size_t)row * 4096)[t] = pack;
}

// ---------------------------------------------------------------------------
// tq[kc] partial = qx @ qa^T over k-chunk kc (512 bytes, 8 MFMA steps).
// One wave per 16-row m-tile per chunk; int32 exact.
__global__ __launch_bounds__(256) void lora_mfma_kernel(const int8_t* __restrict__ Qx,
                                                        const int8_t* __restrict__ Qa,
                                                        int* __restrict__ tqp) {
  const int lane = threadIdx.x & 63;
  const int wv = threadIdx.x >> 6;            // 0..3
  const int m0 = (blockIdx.x * 4 + wv) * 16;  // row-tile base
  const int kc = blockIdx.y;                  // 0..7
  const int8_t* ax =
      Qx + (size_t)(m0 + (lane & 15)) * 4096 + kc * 512 + ((lane >> 4) << 4);
  const int8_t* bx = Qa + (size_t)(lane & 15) * 4096 + kc * 512 + ((lane >> 4) << 4);
  v4i acc = {0, 0, 0, 0};
#pragma unroll
  for (int s = 0; s < 8; ++s) {
    v4i a = *reinterpret_cast<const v4i*>(ax + s * 64);
    v4i b = *reinterpret_cast<const v4i*>(bx + s * 64);
    acc = __builtin_amdgcn_mfma_i32_16x16x64_i8(a, b, acc, 0, 0, 0);
  }
  int* tp = tqp + ((size_t)kc * 8192 + m0) * 16;
#pragma unroll
  for (int rr = 0; rr < 4; ++rr)
    tp[((lane >> 4) * 4 + rr) * 16 + (lane & 15)] = acc[rr];  // C/D: col=l&15
}

__global__ __launch_bounds__(256) void lora_t_reduce_kernel(const int* __restrict__ tqp,
                                                            const float* __restrict__ Sx,
                                                            const float* __restrict__ Sa,
                                                            float* __restrict__ tmat) {
  int i = blockIdx.x * 256 + threadIdx.x;  // 131072 = 8192*16
  int row = i >> 4, r = i & 15;
  int s = 0;
#pragma unroll
  for (int kc = 0; kc < 8; ++kc) s += tqp[(size_t)kc * 131072 + i];
  tmat[i] = (float)s * Sx[row] * Sa[r];
}

// ---------------------------------------------------------------------------
// 256x256 i8 GEMM, REG-STAGED (buffer_load->VGPR->ds_write), 2-ring 64KB LDS.
// 1024 threads = 16 waves (4M x 4N), per-wave 64x64, mfma_i32_16x16x64_i8
// (acc 4x4 v4i = 64 VGPR; conflict-clean frag layout from R5/R8).
// Rationale: global_load_lds DMA path measured at ~8 B/cy/CU per resident
// block (R5/R8) and ~15.5 saturated (R6/R7) -- every prior schedule was
// delivery-bound on it. Reg-staging rides the normal VMEM pipe instead.
// Per step: issue loads(t+2) -> ds_read frags buf(t) -> lgkm0 -> 16 MFMA ->
// ds_write regs(t+1) (compiler-exact vmcnt(2), never drains) -> barrier.
__global__ __launch_bounds__(1024, 4) void gemm_i8_kernel(
    const int8_t* __restrict__ Aq, const int8_t* __restrict__ Bq,
    const float* __restrict__ Sx, const float* __restrict__ Sw,
    const float* __restrict__ Tm, const float* __restrict__ LB,
    float* __restrict__ out) {
  __shared__ __align__(16) char smem[65536];  // 2 x (A 16K + B 16K)

  const int tid = threadIdx.x;
  const int lane = tid & 63;
  const int w = tid >> 6;   // 0..15
  const int wm = w >> 2;    // 0..3
  const int wn = w & 3;     // 0..3

  int bid = (int)blockIdx.x;
  bid = (bid & 7) * 64 + (bid >> 3);  // bijective XCD swizzle (512 % 8 == 0)
  const int bm = bid >> 4;            // 0..31
  const int bn = bid & 15;            // 0..15

  // ---- staging: 1 A-load + 1 B-load per thread per step (32 KB/block/step)
  const int sr = tid >> 2;   // 0..255 (row in both tiles)
  const int sc = tid & 3;    // 16B chunk
  const uint32_t sbase = (uint32_t)(uintptr_t)(void*)smem;
  const uint32_t wAddr =
      sbase + (uint32_t)(sr * 64 + ((sc ^ ((sr >> 1) & 3)) << 4));  // swizzled dest
  const int8_t* Agp = Aq + (size_t)bm * 256 * 4096 + (size_t)sr * 4096 + sc * 16;
  const int8_t* Bgp = Bq + (size_t)bn * 256 * 4096 + (size_t)sr * 4096 + sc * 16;

  // ---- fragment bases (chunk-swizzle invariant under row+=16) ----
  const int cc = lane >> 4;
  const int ar0 = wm * 64 + (lane & 15);
  const int br0 = wn * 64 + (lane & 15);
  const uint32_t aBase = sbase + (uint32_t)(ar0 * 64 + ((cc ^ ((ar0 >> 1) & 3)) << 4));
  const uint32_t bBase = sbase + (uint32_t)(br0 * 64 + ((cc ^ ((br0 >> 1) & 3)) << 4));

  v4i acc[4][4];
#pragma unroll
  for (int i = 0; i < 4; ++i)
#pragma unroll
    for (int n = 0; n < 4; ++n) {
      v4i z = {0, 0, 0, 0};
      acc[i][n] = z;
    }

#define MFMA16()                                                                     \
  do {                                                                               \
    __builtin_amdgcn_s_setprio(1);                                                   \
    _Pragma("unroll") for (int i = 0; i < 4; ++i) _Pragma("unroll") for (int n = 0;  \
                                                                        n < 4; ++n)  \
        acc[i][n] = __builtin_amdgcn_mfma_i32_16x16x64_i8(af[i], bf[n], acc[i][n],   \
                                                          0, 0, 0);                  \
    __builtin_amdgcn_s_setprio(0);                                                   \
  } while (0)

  // ---- prologue: data0 -> buf0 (via regs), data1 in flight ----
  v4i eA = *reinterpret_cast<const v4i*>(Agp);
  v4i eB = *reinterpret_cast<const v4i*>(Bgp);
  v4i oA = *reinterpret_cast<const v4i*>(Agp + 64);
  v4i oB = *reinterpret_cast<const v4i*>(Bgp + 64);
  DSW(wAddr, "0", eA);
  DSW(wAddr, "16384", eB);
  LGKM0();
  __builtin_amdgcn_s_barrier();
  __builtin_amdgcn_sched_barrier(0);

#pragma unroll 1
  for (int i = 0; i < 32; ++i) {
    v4i af[4], bf[4];
    // ================= even step t = 2i (read buf0) =================
    if (i < 31) {
      const int kb = (2 * i + 2) << 6;
      eA = *reinterpret_cast<const v4i*>(Agp + kb);
      eB = *reinterpret_cast<const v4i*>(Bgp + kb);
    }
    __builtin_amdgcn_sched_barrier(0);
    DSR(af[0], aBase, "0");
    DSR(af[1], aBase, "1024");
    DSR(af[2], aBase, "2048");
    DSR(af[3], aBase, "3072");
    DSR(bf[0], bBase, "16384");
    DSR(bf[1], bBase, "17408");
    DSR(bf[2], bBase, "18432");
    DSR(bf[3], bBase, "19456");
    LGKM0();
    MFMA16();
    DSW(wAddr, "32768", oA);  // publish data(t+1) -> buf1 (vmcnt by compiler)
    DSW(wAddr, "49152", oB);
    LGKM0();
    __builtin_amdgcn_s_barrier();
    __builtin_amdgcn_sched_barrier(0);

    // ================= odd step t = 2i+1 (read buf1) =================
    if (i < 31) {
      const int kb = (2 * i + 3) << 6;
      oA = *reinterpret_cast<const v4i*>(Agp + kb);
      oB = *reinterpret_cast<const v4i*>(Bgp + kb);
    }
    __builtin_amdgcn_sched_barrier(0);
    DSR(af[0], aBase, "32768");
    DSR(af[1], aBase, "33792");
    DSR(af[2], aBase, "34816");
    DSR(af[3], aBase, "35840");
    DSR(bf[0], bBase, "49152");
    DSR(bf[1], bBase, "50176");
    DSR(bf[2], bBase, "51200");
    DSR(bf[3], bBase, "52224");
    LGKM0();
    MFMA16();
    if (i < 31) {
      DSW(wAddr, "0", eA);  // publish data(t+1) -> buf0
      DSW(wAddr, "16384", eB);
      LGKM0();
      __builtin_amdgcn_s_barrier();
      __builtin_amdgcn_sched_barrier(0);
    }
  }

  // ---- epilogue: scales + fused LoRA ----
  __syncthreads();
  float* tl = (float*)smem;              // [256][17]
  float* bl = (float*)(smem + 17408);    // [256][17]
  {
    int r = tid >> 2, q4 = (tid & 3) * 4;
    float4 tv = *reinterpret_cast<const float4*>(Tm + (size_t)(bm * 256 + r) * 16 + q4);
    tl[r * 17 + q4 + 0] = tv.x;
    tl[r * 17 + q4 + 1] = tv.y;
    tl[r * 17 + q4 + 2] = tv.z;
    tl[r * 17 + q4 + 3] = tv.w;
    float4 bv = *reinterpret_cast<const float4*>(LB + (size_t)(bn * 256 + r) * 16 + q4);
    bl[r * 17 + q4 + 0] = bv.x;
    bl[r * 17 + q4 + 1] = bv.y;
    bl[r * 17 + q4 + 2] = bv.z;
    bl[r * 17 + q4 + 3] = bv.w;
  }
  __syncthreads();

  float blv[4][16], swv[4];
#pragma unroll
  for (int ni = 0; ni < 4; ++ni) {
    int cl = wn * 64 + ni * 16 + (lane & 15);
    swv[ni] = Sw[bn * 256 + cl];
#pragma unroll
    for (int q = 0; q < 16; ++q) blv[ni][q] = bl[cl * 17 + q];
  }
#pragma unroll
  for (int mi = 0; mi < 4; ++mi) {
#pragma unroll
    for (int rr = 0; rr < 4; ++rr) {
      int rl = wm * 64 + mi * 16 + (lane >> 4) * 4 + rr;  // C/D: row=(l>>4)*4+reg
      float sxv = Sx[bm * 256 + rl];
      float tv[16];
#pragma unroll
      for (int q = 0; q < 16; ++q) tv[q] = tl[rl * 17 + q];
      float* orow = out + (size_t)(bm * 256 + rl) * 4096 + bn * 256;
#pragma unroll
      for (int ni = 0; ni < 4; ++ni) {
        float dot = 0.f;
#pragma unroll
        for (int q = 0; q < 16; ++q) dot = fmaf(tv[q], blv[ni][q], dot);
        int cl = wn * 64 + ni * 16 + (lane & 15);  // C/D: col = l&15
        orow[cl] = sxv * swv[ni] * (float)acc[mi][ni][rr] + 2.0f * dot;
      }
    }
  }
}

// ---------------------------------------------------------------------------
extern "C" void kernel_launch(void* const* d_in, const int* in_sizes, int n_in,
                              void* d_out, int out_size, void* d_ws, size_t ws_size,
                              hipStream_t stream) {
  const float* x = (const float*)d_in[0];     // 8192 x 4096
  const float* wgt = (const float*)d_in[1];   // 4096 x 4096
  const float* lA = (const float*)d_in[2];    // 16 x 4096
  const float* lB = (const float*)d_in[3];    // 4096 x 16
  float* out = (float*)d_out;                 // 8192 x 4096

  char* ws = (char*)d_ws;
  int8_t* qx = (int8_t*)ws;                    // 32 MB
  int8_t* qw = (int8_t*)(ws + 33554432);       // 16 MB
  float* sx = (float*)(ws + 50331648);         // 32 KB
  float* sw = (float*)(ws + 50364416);         // 16 KB
  float* tmat = (float*)(ws + 50380800);       // 512 KB
  int* tqp = (int*)(ws + 50905088);            // 4 MB int32 partials
  int8_t* qa = (int8_t*)(ws + 55099392);       // 64 KB
  float* sa = (float*)(ws + 55164928);         // 64 B

  fwht_quant_kernel<<<8192, 256, 0, stream>>>(x, qx, sx);
  fwht_quant_kernel<<<4096, 256, 0, stream>>>(wgt, qw, sw);
  fwht_quant_kernel<<<16, 256, 0, stream>>>(lA, qa, sa);
  lora_mfma_kernel<<<dim3(128, 8), 256, 0, stream>>>(qx, qa, tqp);
  lora_t_reduce_kernel<<<512, 256, 0, stream>>>(tqp, sx, sa, tmat);
  gemm_i8_kernel<<<512, 1024, 0, stream>>>(qx, qw, sx, sw, tmat, lB, out);
}

// Round 10
// 304.445 us; speedup vs baseline: 1.0367x; 1.0367x over previous
//
#include <hip/hip_runtime.h>
#include <stdint.h>

typedef int v4i __attribute__((ext_vector_type(4)));

#define GLD_LDS16(gp, lp)                                                              \
  __builtin_amdgcn_global_load_lds((const __attribute__((address_space(1))) void*)(gp), \
                                   (__attribute__((address_space(3))) void*)(lp), 16, 0, 0)

__device__ __forceinline__ v4i lds_read_b128(uint32_t off) {
  v4i r;
  asm volatile("ds_read_b128 %0, %1" : "=v"(r) : "v"(off));
  return r;
}

// ---------------------------------------------------------------------------
__device__ __forceinline__ void fwht16(float v[16]) {
#pragma unroll
  for (int h = 1; h < 16; h <<= 1) {
#pragma unroll
    for (int i = 0; i < 16; ++i) {
      if (!(i & h)) {
        float a = v[i], b = v[i | h];
        v[i] = a + b;
        v[i | h] = a - b;
      }
    }
  }
}

__device__ __forceinline__ void fwht_row_load(const float* __restrict__ xr, int t,
                                              float v[16]) {
  const float4* p = reinterpret_cast<const float4*>(xr) + t * 4;
  float4 a = p[0], b = p[1], c = p[2], d = p[3];
  v[0] = a.x; v[1] = a.y; v[2] = a.z; v[3] = a.w;
  v[4] = b.x; v[5] = b.y; v[6] = b.z; v[7] = b.w;
  v[8] = c.x; v[9] = c.y; v[10] = c.z; v[11] = c.w;
  v[12] = d.x; v[13] = d.y; v[14] = d.z; v[15] = d.w;
}

__device__ __forceinline__ void fwht4096(float v[16], float* lds, int t) {
  fwht16(v);
#pragma unroll
  for (int e = 0; e < 16; ++e) {
    int idx = t * 16 + e;
    lds[idx + (idx >> 5)] = v[e];
  }
  __syncthreads();
#pragma unroll
  for (int e = 0; e < 16; ++e) {
    int idx = ((t >> 4) << 8) + (e << 4) + (t & 15);
    v[e] = lds[idx + (idx >> 5)];
  }
  fwht16(v);
#pragma unroll
  for (int e = 0; e < 16; ++e) {
    int idx = ((t >> 4) << 8) + (e << 4) + (t & 15);
    lds[idx + (idx >> 5)] = v[e];
  }
  __syncthreads();
#pragma unroll
  for (int e = 0; e < 16; ++e) {
    int idx = (e << 8) + t;
    v[e] = lds[idx + (idx >> 5)];
  }
  fwht16(v);
#pragma unroll
  for (int e = 0; e < 16; ++e) v[e] *= 0.015625f;  // 1/sqrt(4096)
}

// R5-proven version: direct coalesced byte stores (the R6 LDS byte-transpose
// variant measured ~25us SLOWER across the two big fwht launches).
__global__ __launch_bounds__(256) void fwht_quant_kernel(const float* __restrict__ X,
                                                         int8_t* __restrict__ Q,
                                                         float* __restrict__ S) {
  const int row = blockIdx.x;
  const int t = threadIdx.x;
  __shared__ float lds[4224];
  __shared__ float wred[4];

  float v[16];
  fwht_row_load(X + (size_t)row * 4096, t, v);
  fwht4096(v, lds, t);

  float m = 0.f;
#pragma unroll
  for (int e = 0; e < 16; ++e) m = fmaxf(m, fabsf(v[e]));
#pragma unroll
  for (int off = 32; off > 0; off >>= 1) m = fmaxf(m, __shfl_xor(m, off));
  if ((t & 63) == 0) wred[t >> 6] = m;
  __syncthreads();
  m = fmaxf(fmaxf(wred[0], wred[1]), fmaxf(wred[2], wred[3]));
  const float s = fmaxf(m * (1.0f / 127.0f), 1e-8f);
  if (t == 0) S[row] = s;
  int8_t* qr = Q + (size_t)row * 4096;
#pragma unroll
  for (int e = 0; e < 16; ++e) {
    float q = rintf(v[e] / s);
    q = fminf(fmaxf(q, -127.f), 127.f);
    qr[(e << 8) + t] = (int8_t)(int)q;
  }
}

// ---------------------------------------------------------------------------
// tq[kc] partial = qx @ qa^T over k-chunk kc (512 bytes, 8 MFMA steps). Exact int32.
__global__ __launch_bounds__(256) void lora_mfma_kernel(const int8_t* __restrict__ Qx,
                                                        const int8_t* __restrict__ Qa,
                                                        int* __restrict__ tqp) {
  const int lane = threadIdx.x & 63;
  const int wv = threadIdx.x >> 6;            // 0..3
  const int m0 = (blockIdx.x * 4 + wv) * 16;  // row-tile base
  const int kc = blockIdx.y;                  // 0..7
  const int8_t* ax =
      Qx + (size_t)(m0 + (lane & 15)) * 4096 + kc * 512 + ((lane >> 4) << 4);
  const int8_t* bx = Qa + (size_t)(lane & 15) * 4096 + kc * 512 + ((lane >> 4) << 4);
  v4i acc = {0, 0, 0, 0};
#pragma unroll
  for (int s = 0; s < 8; ++s) {
    v4i a = *reinterpret_cast<const v4i*>(ax + s * 64);
    v4i b = *reinterpret_cast<const v4i*>(bx + s * 64);
    acc = __builtin_amdgcn_mfma_i32_16x16x64_i8(a, b, acc, 0, 0, 0);
  }
  int* tp = tqp + ((size_t)kc * 8192 + m0) * 16;
#pragma unroll
  for (int rr = 0; rr < 4; ++rr)
    tp[((lane >> 4) * 4 + rr) * 16 + (lane & 15)] = acc[rr];  // C/D: col=l&15
}

__global__ __launch_bounds__(256) void lora_t_reduce_kernel(const int* __restrict__ tqp,
                                                            const float* __restrict__ Sx,
                                                            const float* __restrict__ Sa,
                                                            float* __restrict__ tmat) {
  int i = blockIdx.x * 256 + threadIdx.x;  // 131072 = 8192*16
  int row = i >> 4, r = i & 15;
  int s = 0;
#pragma unroll
  for (int kc = 0; kc < 8; ++kc) s += tqp[(size_t)kc * 131072 + i];
  tmat[i] = (float)s * Sx[row] * Sa[r];
}

// ---------------------------------------------------------------------------
// 256x128 i8 GEMM. R7's winning geometry (3-ring 72KB, 2 blocks/CU, never-drain
// vmcnt(3)) + R5/R8's conflict-CLEAN mfma_i32_16x16x64_i8 fragment layout
// (measured 131K conflicts vs 17M for the 32x32 layout). 8 waves = 4M x 2N,
// per-wave 64x64 (acc 4x4 v4i = 64 AGPR; VGPR ~64 -> no spill at 2 blk/CU).
// Per step (BK=64B): stage(t+2) [3 gld_lds]; read af0-3; lgkm(2);
// 8 MFMA (af01 x bf); lgkm(0); vmcnt(3); barrier; preload bf(t+1) [hidden
// under cluster 2]; 8 MFMA (af23 x bf); lgkm(0); bf=bfp.
__global__ __launch_bounds__(512, 4) void gemm_i8_kernel(
    const int8_t* __restrict__ Aq, const int8_t* __restrict__ Bq,
    const float* __restrict__ Sx, const float* __restrict__ Sw,
    const float* __restrict__ Tm, const float* __restrict__ LB,
    float* __restrict__ out) {
  __shared__ __align__(16) char smem[73728];  // 3 x (A 16K + B 8K)

  const int tid = threadIdx.x;
  const int lane = tid & 63;
  const int w = tid >> 6;   // 0..7
  const int wm = w >> 1;    // 0..3 (M quadrant)
  const int wn = w & 1;     // 0..1 (N half)

  int bid = (int)blockIdx.x;
  bid = (bid & 7) * 128 + (bid >> 3);  // bijective XCD swizzle (1024 % 8 == 0)
  const int bm = bid >> 5;             // 0..31
  const int bn = bid & 31;             // 0..31

  const int8_t* Ag = Aq + (size_t)bm * 256 * 4096;
  const int8_t* Bg = Bq + (size_t)bn * 128 * 4096;

  const uint32_t sbase = (uint32_t)(uintptr_t)(void*)smem;

  // ---- staging: 3 loads/wave/step; pre-swizzled source chunk (R5-proven) ----
  const uint32_t srcOff = (uint32_t)(((lane & 3) ^ ((lane >> 3) & 3)) << 4);
  const uint32_t gA0 = (uint32_t)((w * 32 + (lane >> 2)) * 4096) + srcOff;
  const uint32_t gA1 = gA0 + 16 * 4096;
  const uint32_t gB0 = (uint32_t)((w * 16 + (lane >> 2)) * 4096) + srcOff;

#define STAGE_STEP(s, bufbase)                                           \
  do {                                                                   \
    const uint32_t kb = (uint32_t)(s) << 6;                              \
    GLD_LDS16(Ag + kb + gA0, smem + (bufbase) + w * 2048);               \
    GLD_LDS16(Ag + kb + gA1, smem + (bufbase) + w * 2048 + 1024);        \
    GLD_LDS16(Bg + kb + gB0, smem + (bufbase) + 16384 + w * 1024);       \
  } while (0)

  // ---- fragment LDS offsets (16x16x64: rows lane&15, chunk lane>>4) ----
  int aoff[4], boff[4];
  const int cc = lane >> 4;
#pragma unroll
  for (int mi = 0; mi < 4; ++mi) {
    int r = wm * 64 + mi * 16 + (lane & 15);
    aoff[mi] = r * 64 + ((cc ^ ((r >> 1) & 3)) << 4);
  }
#pragma unroll
  for (int ni = 0; ni < 4; ++ni) {
    int r = wn * 64 + ni * 16 + (lane & 15);
    boff[ni] = 16384 + r * 64 + ((cc ^ ((r >> 1) & 3)) << 4);
  }

  v4i acc[4][4];
#pragma unroll
  for (int i = 0; i < 4; ++i)
#pragma unroll
    for (int n = 0; n < 4; ++n) {
      v4i z = {0, 0, 0, 0};
      acc[i][n] = z;
    }

#define MFMA8(M0)                                                              \
  do {                                                                         \
    __builtin_amdgcn_s_setprio(1);                                             \
    _Pragma("unroll") for (int ii = 0; ii < 2; ++ii)                           \
        _Pragma("unroll") for (int n = 0; n < 4; ++n)                          \
        acc[(M0) + ii][n] = __builtin_amdgcn_mfma_i32_16x16x64_i8(             \
            af[(M0) + ii], bf[n], acc[(M0) + ii][n], 0, 0, 0);                 \
    __builtin_amdgcn_s_setprio(0);                                             \
  } while (0)

  // ---- prologue: stage 0,1; preload bf of buf0 ----
  STAGE_STEP(0, 0);
  STAGE_STEP(1, 24576);
  asm volatile("s_waitcnt vmcnt(3)" ::: "memory");  // stage 0 landed
  __builtin_amdgcn_s_barrier();
  __builtin_amdgcn_sched_barrier(0);

  v4i bf[4], bfp[4];
#pragma unroll
  for (int n = 0; n < 4; ++n) bf[n] = lds_read_b128(sbase + boff[n]);

  uint32_t bc = 0, bn1 = 24576, bn2 = 49152;

#pragma unroll 1
  for (int t = 0; t < 64; ++t) {
    if (t <= 61) STAGE_STEP(t + 2, bn2);

    const uint32_t R = sbase + bc;
    v4i af[4];
    af[0] = lds_read_b128(R + aoff[0]);
    af[1] = lds_read_b128(R + aoff[1]);
    af[2] = lds_read_b128(R + aoff[2]);
    af[3] = lds_read_b128(R + aoff[3]);
    asm volatile("s_waitcnt lgkmcnt(2)" ::: "memory");  // bf + af0,af1 ready
    __builtin_amdgcn_sched_barrier(0);
    MFMA8(0);  // af0,af1 x bf
    asm volatile("s_waitcnt lgkmcnt(0)" ::: "memory");  // af2,af3 ready
    __builtin_amdgcn_sched_barrier(0);

    // never-drain: stage(t+1) landed; t+2 stays in flight
    if (t <= 61)
      asm volatile("s_waitcnt vmcnt(3)" ::: "memory");
    else if (t == 62)
      asm volatile("s_waitcnt vmcnt(0)" ::: "memory");
    __builtin_amdgcn_s_barrier();  // buf(t+1) published everywhere
    __builtin_amdgcn_sched_barrier(0);

    if (t < 63) {  // preload bf of buf(t+1), hidden under cluster 2
      const uint32_t Rn = sbase + bn1;
      bfp[0] = lds_read_b128(Rn + boff[0]);
      bfp[1] = lds_read_b128(Rn + boff[1]);
      bfp[2] = lds_read_b128(Rn + boff[2]);
      bfp[3] = lds_read_b128(Rn + boff[3]);
    }

    MFMA8(2);  // af2,af3 x bf
    if (t < 63) {
      asm volatile("s_waitcnt lgkmcnt(0)" ::: "memory");  // bfp ready
      __builtin_amdgcn_sched_barrier(0);
#pragma unroll
      for (int n = 0; n < 4; ++n) bf[n] = bfp[n];
    }

    uint32_t tmp = bc;  // ring rotate
    bc = bn1;
    bn1 = bn2;
    bn2 = tmp;
  }

  // ---- epilogue: scales + fused LoRA ----
  __syncthreads();
  float* tl = (float*)smem;              // [256][17]
  float* bl = (float*)(smem + 17408);    // [128][17]
  for (int i = tid; i < 1024; i += 512) {
    int r = i >> 2, q4 = (i & 3) * 4;
    float4 tv = *reinterpret_cast<const float4*>(Tm + (size_t)(bm * 256 + r) * 16 + q4);
    tl[r * 17 + q4 + 0] = tv.x;
    tl[r * 17 + q4 + 1] = tv.y;
    tl[r * 17 + q4 + 2] = tv.z;
    tl[r * 17 + q4 + 3] = tv.w;
  }
  if (tid < 512) {
    int r = tid >> 2, q4 = (tid & 3) * 4;
    float4 bv = *reinterpret_cast<const float4*>(LB + (size_t)(bn * 128 + r) * 16 + q4);
    bl[r * 17 + q4 + 0] = bv.x;
    bl[r * 17 + q4 + 1] = bv.y;
    bl[r * 17 + q4 + 2] = bv.z;
    bl[r * 17 + q4 + 3] = bv.w;
  }
  __syncthreads();

  float blv[4][16], swv[4];
#pragma unroll
  for (int ni = 0; ni < 4; ++ni) {
    int cl = wn * 64 + ni * 16 + (lane & 15);
    swv[ni] = Sw[bn * 128 + cl];
#pragma unroll
    for (int q = 0; q < 16; ++q) blv[ni][q] = bl[cl * 17 + q];
  }
#pragma unroll
  for (int mi = 0; mi < 4; ++mi) {
#pragma unroll
    for (int rr = 0; rr < 4; ++rr) {
      int rl = wm * 64 + mi * 16 + (lane >> 4) * 4 + rr;  // C/D: row=(l>>4)*4+reg
      float sxv = Sx[bm * 256 + rl];
      float tv[16];
#pragma unroll
      for (int q = 0; q < 16; ++q) tv[q] = tl[rl * 17 + q];
      float* orow = out + (size_t)(bm * 256 + rl) * 4096 + bn * 128;
#pragma unroll
      for (int ni = 0; ni < 4; ++ni) {
        float dot = 0.f;
#pragma unroll
        for (int q = 0; q < 16; ++q) dot = fmaf(tv[q], blv[ni][q], dot);
        int cl = wn * 64 + ni * 16 + (lane & 15);  // C/D: col = l&15
        orow[cl] = sxv * swv[ni] * (float)acc[mi][ni][rr] + 2.0f * dot;
      }
    }
  }
}

// ---------------------------------------------------------------------------
extern "C" void kernel_launch(void* const* d_in, const int* in_sizes, int n_in,
                              void* d_out, int out_size, void* d_ws, size_t ws_size,
                              hipStream_t stream) {
  const float* x = (const float*)d_in[0];     // 8192 x 4096
  const float* wgt = (const float*)d_in[1];   // 4096 x 4096
  const float* lA = (const float*)d_in[2];    // 16 x 4096
  const float* lB = (const float*)d_in[3];    // 4096 x 16
  float* out = (float*)d_out;                 // 8192 x 4096

  char* ws = (char*)d_ws;
  int8_t* qx = (int8_t*)ws;                    // 32 MB
  int8_t* qw = (int8_t*)(ws + 33554432);       // 16 MB
  float* sx = (float*)(ws + 50331648);         // 32 KB
  float* sw = (float*)(ws + 50364416);         // 16 KB
  float* tmat = (float*)(ws + 50380800);       // 512 KB
  int* tqp = (int*)(ws + 50905088);            // 4 MB int32 partials
  int8_t* qa = (int8_t*)(ws + 55099392);       // 64 KB
  float* sa = (float*)(ws + 55164928);         // 64 B

  fwht_quant_kernel<<<8192, 256, 0, stream>>>(x, qx, sx);
  fwht_quant_kernel<<<4096, 256, 0, stream>>>(wgt, qw, sw);
  fwht_quant_kernel<<<16, 256, 0, stream>>>(lA, qa, sa);
  lora_mfma_kernel<<<dim3(128, 8), 256, 0, stream>>>(qx, qa, tqp);
  lora_t_reduce_kernel<<<512, 256, 0, stream>>>(tqp, sx, sa, tmat);
  gemm_i8_kernel<<<1024, 512, 0, stream>>>(qx, qw, sx, sw, tmat, lB, out);
}